// Round 1
// baseline (1191.339 us; speedup 1.0000x reference)
//
#include <hip/hip_runtime.h>
#include <hip/hip_bf16.h>
#include <math.h>

typedef __bf16 bf16_t;
typedef __bf16 bf16x8 __attribute__((ext_vector_type(8)));
typedef float f32x4 __attribute__((ext_vector_type(4)));
typedef unsigned short u16;

#define NB   40
#define NT   20
#define FEA  200
#define HD   1024
#define NOUT 1095
#define NL   12
#define M_ROWS 800      // NB*NT

// ---------------------------------------------------------------------------
// Transpose+convert: src fp32 logical [srcK][srcN] (row stride srcN) ->
// dst bf16 [Np][Kp] with dst[n][k] = (k<srcK && n<srcN) ? src[k][n] : 0.
// 64x64 tile per block via LDS (pitch 66 u16: odd-dword stride -> conflict-free).
// blockIdx.z = layer (src += z*srcK*srcN, dst += z*Np*Kp).
// ---------------------------------------------------------------------------
__global__ __launch_bounds__(256)
void transpose_convert(const float* __restrict__ src, bf16_t* __restrict__ dst,
                       int srcK, int srcN, int Kp, int Np)
{
    __shared__ u16 tile[64 * 66];
    const int t = threadIdx.x;
    src += (size_t)blockIdx.z * srcK * srcN;
    dst += (size_t)blockIdx.z * Np * Kp;
    const int n0 = blockIdx.x << 6, k0 = blockIdx.y << 6;

    // load: thread t -> col n0+(t&63) (coalesced across lanes), 16 rows
    {
        const int nl = t & 63, kb = (t >> 6) << 4;
        const int gn = n0 + nl;
        #pragma unroll
        for (int j = 0; j < 16; j++) {
            const int gk = k0 + kb + j;
            float v = (gk < srcK && gn < srcN) ? src[(size_t)gk * srcN + gn] : 0.f;
            bf16_t b = (bf16_t)v;
            tile[nl * 66 + kb + j] = *(const u16*)&b;
        }
    }
    __syncthreads();
    // store: thread t -> dst row n0+(t>>2), k chunk k0+(t&3)*16, 2x uint4
    {
        const int nl = t >> 2, kg = (t & 3) << 4;
        const unsigned* tp = (const unsigned*)tile;
        const int dw = nl * 33 + (kg >> 1);
        uint4 v0, v1;
        v0.x = tp[dw+0]; v0.y = tp[dw+1]; v0.z = tp[dw+2]; v0.w = tp[dw+3];
        v1.x = tp[dw+4]; v1.y = tp[dw+5]; v1.z = tp[dw+6]; v1.w = tp[dw+7];
        bf16_t* dp = dst + (size_t)(n0 + nl) * Kp + k0 + kg;
        *(uint4*)dp = v0;
        *(uint4*)(dp + 8) = v1;
    }
}

// x [800][200] fp32 -> xb [800][256] bf16, zero-padded K. grid 800 x 256thr.
__global__ __launch_bounds__(256)
void convert_pad_x(const float* __restrict__ src, bf16_t* __restrict__ dst)
{
    const int m = blockIdx.x, k = threadIdx.x;
    dst[m * 256 + k] = (bf16_t)((k < FEA) ? src[(size_t)m * FEA + k] : 0.f);
}

// ---------------------------------------------------------------------------
// Direct-fragment GEMM: C[M,Nstore] = A[M,Ks]bf16 @ Bt[n][k]bf16 (+bias fp32)
// (+relu / +SRU-gate sigmoid). No LDS, no barriers.
// Block 256 thr: wave w -> row-tile blockIdx.y*4+w (rows clamped to M-1),
// 4 col-tiles at n0=blockIdx.x*64. MFMA 16x16x32 bf16.
// Verified layouts: A[m=l16][k=quad*8+j], B[n=l16][k=quad*8+j],
// D col=l16, row=quad*4+reg.
// GATES mode (fp32 out, Nstore=3*HD): col<HD passes through (x_tilde, no
// bias); col>=HD gets v = sigmoid(v + bias[col-HD]) (bias = [b_f | b_r]).
// ---------------------------------------------------------------------------
template<bool OUT_F32, bool RELU, bool GATES>
__global__ __launch_bounds__(256)
void gemm_tn(const bf16_t* __restrict__ A, const bf16_t* __restrict__ Bt,
             const float* __restrict__ bias, void* __restrict__ C,
             int M, int Nstore, int Ks)
{
    const int tid = threadIdx.x;
    const int w = tid >> 6, lane = tid & 63, quad = lane >> 4, l16 = lane & 15;
    const int n0 = blockIdx.x << 6;
    const int r0 = (blockIdx.y * 4 + w) << 4;

    int arow = r0 + l16; if (arow > M - 1) arow = M - 1;
    const bf16_t* ap = A + (size_t)arow * Ks + quad * 8;
    const bf16_t* bp[4];
    #pragma unroll
    for (int ct = 0; ct < 4; ct++)
        bp[ct] = Bt + (size_t)(n0 + ct * 16 + l16) * Ks + quad * 8;

    f32x4 acc[4];
    #pragma unroll
    for (int i = 0; i < 4; i++) acc[i] = (f32x4){0.f, 0.f, 0.f, 0.f};

    #pragma unroll 2
    for (int k0 = 0; k0 < Ks; k0 += 32) {
        bf16x8 a = *(const bf16x8*)(ap + k0);
        #pragma unroll
        for (int ct = 0; ct < 4; ct++) {
            bf16x8 b = *(const bf16x8*)(bp[ct] + k0);
            acc[ct] = __builtin_amdgcn_mfma_f32_16x16x32_bf16(a, b, acc[ct], 0, 0, 0);
        }
    }

    #pragma unroll
    for (int ct = 0; ct < 4; ct++) {
        const int col = n0 + ct * 16 + l16;
        if (col >= Nstore) continue;
        float bv = 0.f;
        if (GATES) { if (col >= HD) bv = bias[col - HD]; }
        else if (bias) bv = bias[col];
        #pragma unroll
        for (int i = 0; i < 4; i++) {
            const int m = r0 + quad * 4 + i;
            if (m < M) {
                float v = acc[ct][i] + bv;
                if (RELU) v = v > 0.f ? v : 0.f;
                if (GATES && col >= HD) v = 1.f / (1.f + __expf(-v));
                if (OUT_F32) ((float*)C)[(size_t)m * Nstore + col] = v;
                else         ((bf16_t*)C)[(size_t)m * Nstore + col] = (bf16_t)v;
            }
        }
    }
}

// ---------------------------------------------------------------------------
// SRU recurrence over pre-activated U fp32 [800][3072] = [x_tilde | f | r]
// (f, r already sigmoided in the GEMM epilogue). One thread per (batch, h):
// 40960 threads = 160 blocks x 256. T=20 fully unrolled: all 80 loads are
// c-chain-independent -> deep ILP covers latency despite the small grid.
// ---------------------------------------------------------------------------
__global__ __launch_bounds__(256)
void sru_recur(const float* __restrict__ U, const bf16_t* __restrict__ hin,
               bf16_t* __restrict__ hout, const float* __restrict__ c0,
               float* __restrict__ cout)
{
    const int idx = blockIdx.x * 256 + threadIdx.x;   // b*HD + h
    const int b = idx >> 10;
    float c = c0[idx];
    const float*  ub = U    + (size_t)b * NT * 3 * HD + (idx & 1023);
    const bf16_t* hb = hin  + (size_t)b * NT * HD     + (idx & 1023);
    bf16_t*       ho = hout + (size_t)b * NT * HD     + (idx & 1023);
    #pragma unroll
    for (int t = 0; t < NT; t++) {
        const float xt = ub[t * 3 * HD];
        const float f  = ub[t * 3 * HD + HD];
        const float r  = ub[t * 3 * HD + 2 * HD];
        c = f * c + (1.f - f) * xt;
        const float hp = (float)hb[t * HD];
        ho[t * HD] = (bf16_t)(r * tanhf(c) + (1.f - r) * hp);
    }
    cout[idx] = c;
}

// ---------------------------------------------------------------------------
extern "C" void kernel_launch(void* const* d_in, const int* in_sizes, int n_in,
                              void* d_out, int out_size, void* d_ws, size_t ws_size,
                              hipStream_t stream)
{
    const float* x      = (const float*)d_in[0];
    const float* hidden = (const float*)d_in[1];
    const float* W1     = (const float*)d_in[2];
    const float* b1     = (const float*)d_in[3];
    const float* sruW   = (const float*)d_in[4];
    const float* srub   = (const float*)d_in[5];
    const float* W3     = (const float*)d_in[6];
    const float* b3     = (const float*)d_in[7];
    const float* W4     = (const float*)d_in[8];
    const float* b4     = (const float*)d_in[9];

    float* out     = (float*)d_out;
    float* hid_out = out + (size_t)M_ROWS * NOUT;          // [12,40,1024] fp32

    // h0 (bf16, 1.64 MB) lives in d_out's out0 region (3.50 MB fp32, dead
    // until the final GEMM fully overwrites it; final GEMM reads only g).
    bf16_t* h0 = (bf16_t*)d_out;

    char* ws = (char*)d_ws;
    const size_t SZ_WT  = (size_t)NL * 3 * HD * HD * 2;    // 75,497,472
    const size_t SZ_W1  = (size_t)HD * 256 * 2;            //    524,288
    const size_t SZ_W3  = (size_t)HD * HD * 2;             //  2,097,152
    const size_t SZ_W4  = (size_t)1152 * HD * 2;           //  2,359,296
    const size_t SZ_XB  = (size_t)M_ROWS * 256 * 2;        //    409,600
    const size_t SZ_H   = (size_t)M_ROWS * HD * 2;         //  1,638,400
    const size_t SZ_U   = (size_t)M_ROWS * 3 * HD * 4;     //  9,830,400
    const size_t SLOT   = (size_t)3 * HD * HD * 2;         //  6,291,456
    const size_t FAST_NEED = SZ_WT + SZ_W1 + SZ_W3 + SZ_W4 + SZ_XB + 2 * SZ_H + SZ_U;
    const bool fast = ws_size >= FAST_NEED;

    const dim3 blk(256);

    if (fast) {
        bf16_t* wt  = (bf16_t*)ws;
        bf16_t* w1t = (bf16_t*)(ws + SZ_WT);
        bf16_t* w3t = (bf16_t*)(ws + SZ_WT + SZ_W1);
        bf16_t* w4t = (bf16_t*)(ws + SZ_WT + SZ_W1 + SZ_W3);
        bf16_t* xb  = (bf16_t*)(ws + SZ_WT + SZ_W1 + SZ_W3 + SZ_W4);
        bf16_t* h1  = (bf16_t*)(ws + SZ_WT + SZ_W1 + SZ_W3 + SZ_W4 + SZ_XB);
        bf16_t* g   = (bf16_t*)(ws + SZ_WT + SZ_W1 + SZ_W3 + SZ_W4 + SZ_XB + SZ_H);
        float*  U   = (float*) (ws + SZ_WT + SZ_W1 + SZ_W3 + SZ_W4 + SZ_XB + 2 * SZ_H);

        convert_pad_x<<<M_ROWS, blk, 0, stream>>>(x, xb);
        transpose_convert<<<dim3(16, 4, 1),  blk, 0, stream>>>(W1,   w1t, FEA, HD,    256, HD);
        transpose_convert<<<dim3(48, 16, NL), blk, 0, stream>>>(sruW, wt,  HD,  3*HD, HD,  3*HD);
        transpose_convert<<<dim3(16, 16, 1), blk, 0, stream>>>(W3,   w3t, HD,  HD,   HD,  HD);
        transpose_convert<<<dim3(18, 16, 1), blk, 0, stream>>>(W4,   w4t, HD,  NOUT, HD,  1152);

        gemm_tn<false, false, false><<<dim3(16, 13), blk, 0, stream>>>(xb, w1t, b1, h0, M_ROWS, HD, 256);

        for (int l = 0; l < NL; l++) {
            const bf16_t* hi = (l & 1) ? h1 : h0;
            bf16_t*       ho = (l & 1) ? h0 : h1;
            gemm_tn<true, false, true><<<dim3(48, 13), blk, 0, stream>>>(
                hi, wt + (size_t)l * 3 * HD * HD, srub + (size_t)l * 2 * HD,
                U, M_ROWS, 3 * HD, HD);
            sru_recur<<<dim3(160), blk, 0, stream>>>(
                U, hi, ho, hidden + (size_t)l * NB * HD,
                hid_out + (size_t)l * NB * HD);
        }
        // final h in h0
        gemm_tn<false, true, false><<<dim3(16, 13), blk, 0, stream>>>(h0, w3t, b3, g, M_ROWS, HD, HD);
        gemm_tn<true, false, false><<<dim3(18, 13), blk, 0, stream>>>(g, w4t, b4, out, M_ROWS, NOUT, HD);
    } else {
        bf16_t* slot = (bf16_t*)ws;                        // reused per weight
        bf16_t* xb   = (bf16_t*)(ws + SLOT);
        bf16_t* h1   = (bf16_t*)(ws + SLOT + SZ_XB);
        bf16_t* g    = (bf16_t*)(ws + SLOT + SZ_XB + SZ_H);
        float*  U    = (float*) (ws + SLOT + SZ_XB + SZ_H + SZ_H);

        convert_pad_x<<<M_ROWS, blk, 0, stream>>>(x, xb);
        transpose_convert<<<dim3(16, 4, 1), blk, 0, stream>>>(W1, slot, FEA, HD, 256, HD);
        gemm_tn<false, false, false><<<dim3(16, 13), blk, 0, stream>>>(xb, slot, b1, h0, M_ROWS, HD, 256);

        for (int l = 0; l < NL; l++) {
            transpose_convert<<<dim3(48, 16, 1), blk, 0, stream>>>(
                sruW + (size_t)l * HD * 3 * HD, slot, HD, 3*HD, HD, 3*HD);
            const bf16_t* hi = (l & 1) ? h1 : h0;
            bf16_t*       ho = (l & 1) ? h0 : h1;
            gemm_tn<true, false, true><<<dim3(48, 13), blk, 0, stream>>>(
                hi, slot, srub + (size_t)l * 2 * HD, U, M_ROWS, 3 * HD, HD);
            sru_recur<<<dim3(160), blk, 0, stream>>>(
                U, hi, ho, hidden + (size_t)l * NB * HD,
                hid_out + (size_t)l * NB * HD);
        }
        transpose_convert<<<dim3(16, 16, 1), blk, 0, stream>>>(W3, slot, HD, HD, HD, HD);
        gemm_tn<false, true, false><<<dim3(16, 13), blk, 0, stream>>>(h0, slot, b3, g, M_ROWS, HD, HD);
        transpose_convert<<<dim3(18, 16, 1), blk, 0, stream>>>(W4, slot, HD, NOUT, HD, 1152);
        gemm_tn<true, false, false><<<dim3(18, 13), blk, 0, stream>>>(g, slot, b4, out, M_ROWS, NOUT, HD);
    }
}

// Round 2
// 685.825 us; speedup vs baseline: 1.7371x; 1.7371x over previous
//
#include <hip/hip_runtime.h>
#include <hip/hip_bf16.h>
#include <math.h>

typedef __bf16 bf16_t;
typedef __bf16 bf16x8 __attribute__((ext_vector_type(8)));
typedef float f32x4 __attribute__((ext_vector_type(4)));
typedef unsigned short u16;

#define NB   40
#define NT   20
#define FEA  200
#define HD   1024
#define NOUT 1095
#define NL   12
#define M_ROWS 800      // NB*NT

// ---------------------------------------------------------------------------
// Transpose+convert: src fp32 logical [srcK][srcN] (row stride srcN) ->
// dst bf16 [Np][Kp] with dst[n][k] = (k<srcK && n<srcN) ? src[k][n] : 0.
// ---------------------------------------------------------------------------
__global__ __launch_bounds__(256)
void transpose_convert(const float* __restrict__ src, bf16_t* __restrict__ dst,
                       int srcK, int srcN, int Kp, int Np)
{
    __shared__ u16 tile[64 * 66];
    const int t = threadIdx.x;
    src += (size_t)blockIdx.z * srcK * srcN;
    dst += (size_t)blockIdx.z * Np * Kp;
    const int n0 = blockIdx.x << 6, k0 = blockIdx.y << 6;
    {
        const int nl = t & 63, kb = (t >> 6) << 4;
        const int gn = n0 + nl;
        #pragma unroll
        for (int j = 0; j < 16; j++) {
            const int gk = k0 + kb + j;
            float v = (gk < srcK && gn < srcN) ? src[(size_t)gk * srcN + gn] : 0.f;
            bf16_t b = (bf16_t)v;
            tile[nl * 66 + kb + j] = *(const u16*)&b;
        }
    }
    __syncthreads();
    {
        const int nl = t >> 2, kg = (t & 3) << 4;
        const unsigned* tp = (const unsigned*)tile;
        const int dw = nl * 33 + (kg >> 1);
        uint4 v0, v1;
        v0.x = tp[dw+0]; v0.y = tp[dw+1]; v0.z = tp[dw+2]; v0.w = tp[dw+3];
        v1.x = tp[dw+4]; v1.y = tp[dw+5]; v1.z = tp[dw+6]; v1.w = tp[dw+7];
        bf16_t* dp = dst + (size_t)(n0 + nl) * Kp + k0 + kg;
        *(uint4*)dp = v0;
        *(uint4*)(dp + 8) = v1;
    }
}

// x [800][200] fp32 -> xb [800][256] bf16, zero-padded K.
__global__ __launch_bounds__(256)
void convert_pad_x(const float* __restrict__ src, bf16_t* __restrict__ dst)
{
    const int m = blockIdx.x, k = threadIdx.x;
    dst[m * 256 + k] = (bf16_t)((k < FEA) ? src[(size_t)m * FEA + k] : 0.f);
}

// ---------------------------------------------------------------------------
// LDS-tiled GEMM (m97 structure): C[M,Nstore] = A[M,Ks]bf16 @ Bt[n][k]bf16.
// BM=128, BN=64, BK=64; 4 waves, each owns a 64x32 quadrant (4x2 frags of
// 16x16x32). Staging via global_load_lds width=16 with PRE-SWIZZLED global
// source (rule #21): LDS written linearly lane-ordered; LDS(r, slot s) holds
// global 16B-slot s ^ (r&7); ds_read_b128 applies the same XOR -> bank-
// conflict-free (G4). 2-phase double buffer: stage tile t+1, compute tile t,
// one __syncthreads per tile (T3-minimum recipe). LDS 2x24KB.
// Epilogues: bias(+relu) or GATES (col>=HD: sigmoid(v + bias[col-HD])).
// Requires: Ks % 64 == 0, N % 64 == 0 (store guarded by Nstore, rows by M).
// ---------------------------------------------------------------------------
template<bool OUT_F32, bool RELU, bool GATES>
__global__ __launch_bounds__(256)
void gemm_tiled(const bf16_t* __restrict__ A, const bf16_t* __restrict__ Bt,
                const float* __restrict__ bias, void* __restrict__ C,
                int M, int Nstore, int Ks)
{
    __shared__ char lds[2][24576];          // per buf: A 16KB + B 8KB
    const int tid = threadIdx.x;
    const int w = tid >> 6, lane = tid & 63, quad = lane >> 4, l16 = lane & 15;
    const int n0 = blockIdx.x << 6;         // BN=64
    const int m0 = blockIdx.y << 7;         // BM=128
    const int wr = w >> 1, wc = w & 1;      // quadrant: rows wr*64, cols wc*32

    // staging: chunk = 8 rows x 64k (1KB). lane -> row lane>>3, 16B slot lane&7.
    // global k-slot pre-swizzled: (lane&7) ^ (lane>>3)  [= slot ^ (row&7)]
    const int lrow  = lane >> 3;
    const int gslot = ((lane & 7) ^ lrow) << 3;   // element offset
    const bf16_t* aSrc[4];
    const bf16_t* bSrc[2];
    #pragma unroll
    for (int i = 0; i < 4; i++) {
        int r = m0 + (w * 4 + i) * 8 + lrow;
        if (r > M - 1) r = M - 1;
        aSrc[i] = A + (size_t)r * Ks + gslot;
    }
    #pragma unroll
    for (int i = 0; i < 2; i++)
        bSrc[i] = Bt + (size_t)(n0 + (w * 2 + i) * 8 + lrow) * Ks + gslot;

    f32x4 acc[4][2];
    #pragma unroll
    for (int m = 0; m < 4; m++)
        #pragma unroll
        for (int n = 0; n < 2; n++) acc[m][n] = (f32x4){0.f, 0.f, 0.f, 0.f};

    const int nkt = Ks >> 6;

    #define STAGE(p, kt) do {                                                  \
        const int _k0 = (kt) << 6;                                             \
        char* _b = &lds[p][0];                                                 \
        _Pragma("unroll")                                                      \
        for (int _i = 0; _i < 4; _i++)                                         \
            __builtin_amdgcn_global_load_lds(                                  \
                (const __attribute__((address_space(1))) void*)(aSrc[_i] + _k0),\
                (__attribute__((address_space(3))) void*)(_b + (w * 4 + _i) * 1024), \
                16, 0, 0);                                                     \
        _Pragma("unroll")                                                      \
        for (int _i = 0; _i < 2; _i++)                                         \
            __builtin_amdgcn_global_load_lds(                                  \
                (const __attribute__((address_space(1))) void*)(bSrc[_i] + _k0),\
                (__attribute__((address_space(3))) void*)(_b + 16384 + (w * 2 + _i) * 1024), \
                16, 0, 0);                                                     \
    } while (0)

    STAGE(0, 0);
    __syncthreads();

    for (int kt = 0; kt < nkt; kt++) {
        const int p = kt & 1;
        if (kt + 1 < nkt) STAGE(p ^ 1, kt + 1);
        const char* ab = &lds[p][0];
        #pragma unroll
        for (int kk = 0; kk < 2; kk++) {
            const int ts = (kk << 2) + quad;          // k 16B-slot 0..7
            bf16x8 a[4], b[2];
            #pragma unroll
            for (int m = 0; m < 4; m++) {
                const int r = wr * 64 + m * 16 + l16;
                a[m] = *(const bf16x8*)(ab + r * 128 + ((ts ^ (r & 7)) << 4));
            }
            #pragma unroll
            for (int n = 0; n < 2; n++) {
                const int r = wc * 32 + n * 16 + l16;
                b[n] = *(const bf16x8*)(ab + 16384 + r * 128 + ((ts ^ (r & 7)) << 4));
            }
            #pragma unroll
            for (int m = 0; m < 4; m++)
                #pragma unroll
                for (int n = 0; n < 2; n++)
                    acc[m][n] = __builtin_amdgcn_mfma_f32_16x16x32_bf16(a[m], b[n], acc[m][n], 0, 0, 0);
        }
        __syncthreads();
    }
    #undef STAGE

    // epilogue: D col=l16, row=quad*4+i (verified layout)
    #pragma unroll
    for (int n = 0; n < 2; n++) {
        const int col = n0 + wc * 32 + n * 16 + l16;
        if (col >= Nstore) continue;
        float bv = 0.f;
        if (GATES) { if (col >= HD) bv = bias[col - HD]; }
        else if (bias) bv = bias[col];
        #pragma unroll
        for (int m = 0; m < 4; m++) {
            #pragma unroll
            for (int i = 0; i < 4; i++) {
                const int mg = m0 + wr * 64 + m * 16 + quad * 4 + i;
                if (mg < M) {
                    float v = acc[m][n][i] + bv;
                    if (RELU) v = v > 0.f ? v : 0.f;
                    if (GATES && col >= HD) v = 1.f / (1.f + __expf(-v));
                    if (OUT_F32) ((float*)C)[(size_t)mg * Nstore + col] = v;
                    else         ((bf16_t*)C)[(size_t)mg * Nstore + col] = (bf16_t)v;
                }
            }
        }
    }
}

// ---------------------------------------------------------------------------
// SRU recurrence over pre-activated U fp32 [800][3072] = [x_tilde | f | r].
// One thread per (batch, h); T=20 fully unrolled.
// ---------------------------------------------------------------------------
__global__ __launch_bounds__(256)
void sru_recur(const float* __restrict__ U, const bf16_t* __restrict__ hin,
               bf16_t* __restrict__ hout, const float* __restrict__ c0,
               float* __restrict__ cout)
{
    const int idx = blockIdx.x * 256 + threadIdx.x;   // b*HD + h
    const int b = idx >> 10;
    float c = c0[idx];
    const float*  ub = U    + (size_t)b * NT * 3 * HD + (idx & 1023);
    const bf16_t* hb = hin  + (size_t)b * NT * HD     + (idx & 1023);
    bf16_t*       ho = hout + (size_t)b * NT * HD     + (idx & 1023);
    #pragma unroll
    for (int t = 0; t < NT; t++) {
        const float xt = ub[t * 3 * HD];
        const float f  = ub[t * 3 * HD + HD];
        const float r  = ub[t * 3 * HD + 2 * HD];
        c = f * c + (1.f - f) * xt;
        const float hp = (float)hb[t * HD];
        ho[t * HD] = (bf16_t)(r * tanhf(c) + (1.f - r) * hp);
    }
    cout[idx] = c;
}

// ---------------------------------------------------------------------------
extern "C" void kernel_launch(void* const* d_in, const int* in_sizes, int n_in,
                              void* d_out, int out_size, void* d_ws, size_t ws_size,
                              hipStream_t stream)
{
    const float* x      = (const float*)d_in[0];
    const float* hidden = (const float*)d_in[1];
    const float* W1     = (const float*)d_in[2];
    const float* b1     = (const float*)d_in[3];
    const float* sruW   = (const float*)d_in[4];
    const float* srub   = (const float*)d_in[5];
    const float* W3     = (const float*)d_in[6];
    const float* b3     = (const float*)d_in[7];
    const float* W4     = (const float*)d_in[8];
    const float* b4     = (const float*)d_in[9];

    float* out     = (float*)d_out;
    float* hid_out = out + (size_t)M_ROWS * NOUT;          // [12,40,1024] fp32

    // h0 (bf16) lives in d_out's out0 region (dead until final GEMM overwrites).
    bf16_t* h0 = (bf16_t*)d_out;

    char* ws = (char*)d_ws;
    const size_t SZ_WT  = (size_t)NL * 3 * HD * HD * 2;    // 75,497,472
    const size_t SZ_W1  = (size_t)HD * 256 * 2;
    const size_t SZ_W3  = (size_t)HD * HD * 2;
    const size_t SZ_W4  = (size_t)1152 * HD * 2;
    const size_t SZ_XB  = (size_t)M_ROWS * 256 * 2;
    const size_t SZ_H   = (size_t)M_ROWS * HD * 2;
    const size_t SZ_U   = (size_t)M_ROWS * 3 * HD * 4;     //  9,830,400
    const size_t SLOT   = (size_t)3 * HD * HD * 2;
    const size_t FAST_NEED = SZ_WT + SZ_W1 + SZ_W3 + SZ_W4 + SZ_XB + 2 * SZ_H + SZ_U;
    const bool fast = ws_size >= FAST_NEED;

    const dim3 blk(256);
    const int GY = (M_ROWS + 127) >> 7;                    // 7 row-blocks

    if (fast) {
        bf16_t* wt  = (bf16_t*)ws;
        bf16_t* w1t = (bf16_t*)(ws + SZ_WT);
        bf16_t* w3t = (bf16_t*)(ws + SZ_WT + SZ_W1);
        bf16_t* w4t = (bf16_t*)(ws + SZ_WT + SZ_W1 + SZ_W3);
        bf16_t* xb  = (bf16_t*)(ws + SZ_WT + SZ_W1 + SZ_W3 + SZ_W4);
        bf16_t* h1  = (bf16_t*)(ws + SZ_WT + SZ_W1 + SZ_W3 + SZ_W4 + SZ_XB);
        bf16_t* g   = (bf16_t*)(ws + SZ_WT + SZ_W1 + SZ_W3 + SZ_W4 + SZ_XB + SZ_H);
        float*  U   = (float*) (ws + SZ_WT + SZ_W1 + SZ_W3 + SZ_W4 + SZ_XB + 2 * SZ_H);

        convert_pad_x<<<M_ROWS, blk, 0, stream>>>(x, xb);
        transpose_convert<<<dim3(16, 4, 1),  blk, 0, stream>>>(W1,   w1t, FEA, HD,    256, HD);
        transpose_convert<<<dim3(48, 16, NL), blk, 0, stream>>>(sruW, wt,  HD,  3*HD, HD,  3*HD);
        transpose_convert<<<dim3(16, 16, 1), blk, 0, stream>>>(W3,   w3t, HD,  HD,   HD,  HD);
        transpose_convert<<<dim3(18, 16, 1), blk, 0, stream>>>(W4,   w4t, HD,  NOUT, HD,  1152);

        gemm_tiled<false, false, false><<<dim3(16, GY), blk, 0, stream>>>(xb, w1t, b1, h0, M_ROWS, HD, 256);

        for (int l = 0; l < NL; l++) {
            const bf16_t* hi = (l & 1) ? h1 : h0;
            bf16_t*       ho = (l & 1) ? h0 : h1;
            gemm_tiled<true, false, true><<<dim3(48, GY), blk, 0, stream>>>(
                hi, wt + (size_t)l * 3 * HD * HD, srub + (size_t)l * 2 * HD,
                U, M_ROWS, 3 * HD, HD);
            sru_recur<<<dim3(160), blk, 0, stream>>>(
                U, hi, ho, hidden + (size_t)l * NB * HD,
                hid_out + (size_t)l * NB * HD);
        }
        gemm_tiled<false, true, false><<<dim3(16, GY), blk, 0, stream>>>(h0, w3t, b3, g, M_ROWS, HD, HD);
        gemm_tiled<true, false, false><<<dim3(18, GY), blk, 0, stream>>>(g, w4t, b4, out, M_ROWS, NOUT, HD);
    } else {
        bf16_t* slot = (bf16_t*)ws;
        bf16_t* xb   = (bf16_t*)(ws + SLOT);
        bf16_t* h1   = (bf16_t*)(ws + SLOT + SZ_XB);
        bf16_t* g    = (bf16_t*)(ws + SLOT + SZ_XB + SZ_H);
        float*  U    = (float*) (ws + SLOT + SZ_XB + SZ_H + SZ_H);

        convert_pad_x<<<M_ROWS, blk, 0, stream>>>(x, xb);
        transpose_convert<<<dim3(16, 4, 1), blk, 0, stream>>>(W1, slot, FEA, HD, 256, HD);
        gemm_tiled<false, false, false><<<dim3(16, GY), blk, 0, stream>>>(xb, slot, b1, h0, M_ROWS, HD, 256);

        for (int l = 0; l < NL; l++) {
            transpose_convert<<<dim3(48, 16, 1), blk, 0, stream>>>(
                sruW + (size_t)l * HD * 3 * HD, slot, HD, 3*HD, HD, 3*HD);
            const bf16_t* hi = (l & 1) ? h1 : h0;
            bf16_t*       ho = (l & 1) ? h0 : h1;
            gemm_tiled<true, false, true><<<dim3(48, GY), blk, 0, stream>>>(
                hi, slot, srub + (size_t)l * 2 * HD, U, M_ROWS, 3 * HD, HD);
            sru_recur<<<dim3(160), blk, 0, stream>>>(
                U, hi, ho, hidden + (size_t)l * NB * HD,
                hid_out + (size_t)l * NB * HD);
        }
        transpose_convert<<<dim3(16, 16, 1), blk, 0, stream>>>(W3, slot, HD, HD, HD, HD);
        gemm_tiled<false, true, false><<<dim3(16, GY), blk, 0, stream>>>(h0, slot, b3, g, M_ROWS, HD, HD);
        transpose_convert<<<dim3(18, 16, 1), blk, 0, stream>>>(W4, slot, HD, NOUT, HD, 1152);
        gemm_tiled<true, false, false><<<dim3(18, GY), blk, 0, stream>>>(g, slot, b4, out, M_ROWS, NOUT, HD);
    }
}

// Round 3
// 551.936 us; speedup vs baseline: 2.1585x; 1.2426x over previous
//
#include <hip/hip_runtime.h>
#include <hip/hip_bf16.h>
#include <math.h>

typedef __bf16 bf16_t;
typedef __bf16 bf16x8 __attribute__((ext_vector_type(8)));
typedef float f32x4 __attribute__((ext_vector_type(4)));
typedef unsigned short u16;

#define NB   40
#define NT   20
#define FEA  200
#define HD   1024
#define NOUT 1095
#define NL   12
#define M_ROWS 800      // NB*NT
#define LDSB 34816      // fused dbuf half: A 80x64x2 (10240) + B 192x64x2 (24576)
#define UPITCH 196      // fp32 pitch for U in LDS (192 + 4 pad)

// ---------------------------------------------------------------------------
// Transpose+convert: src fp32 logical [srcK][srcN] (row stride srcN) ->
// dst bf16 [Np][Kp] with dst[n][k] = (k<srcK && n<srcN) ? src[k][n] : 0.
// ---------------------------------------------------------------------------
__global__ __launch_bounds__(256)
void transpose_convert(const float* __restrict__ src, bf16_t* __restrict__ dst,
                       int srcK, int srcN, int Kp, int Np)
{
    __shared__ u16 tile[64 * 66];
    const int t = threadIdx.x;
    src += (size_t)blockIdx.z * srcK * srcN;
    dst += (size_t)blockIdx.z * Np * Kp;
    const int n0 = blockIdx.x << 6, k0 = blockIdx.y << 6;
    {
        const int nl = t & 63, kb = (t >> 6) << 4;
        const int gn = n0 + nl;
        #pragma unroll
        for (int j = 0; j < 16; j++) {
            const int gk = k0 + kb + j;
            float v = (gk < srcK && gn < srcN) ? src[(size_t)gk * srcN + gn] : 0.f;
            bf16_t b = (bf16_t)v;
            tile[nl * 66 + kb + j] = *(const u16*)&b;
        }
    }
    __syncthreads();
    {
        const int nl = t >> 2, kg = (t & 3) << 4;
        const unsigned* tp = (const unsigned*)tile;
        const int dw = nl * 33 + (kg >> 1);
        uint4 v0, v1;
        v0.x = tp[dw+0]; v0.y = tp[dw+1]; v0.z = tp[dw+2]; v0.w = tp[dw+3];
        v1.x = tp[dw+4]; v1.y = tp[dw+5]; v1.z = tp[dw+6]; v1.w = tp[dw+7];
        bf16_t* dp = dst + (size_t)(n0 + nl) * Kp + k0 + kg;
        *(uint4*)dp = v0;
        *(uint4*)(dp + 8) = v1;
    }
}

// x [800][200] fp32 -> xb [800][256] bf16, zero-padded K.
__global__ __launch_bounds__(256)
void convert_pad_x(const float* __restrict__ src, bf16_t* __restrict__ dst)
{
    const int m = blockIdx.x, k = threadIdx.x;
    dst[m * 256 + k] = (bf16_t)((k < FEA) ? src[(size_t)m * FEA + k] : 0.f);
}

// ---------------------------------------------------------------------------
// LDS-tiled dense GEMM (m97 structure, verified round 2): C = A @ Bt^T.
// BM=128, BN=64, BK=64; 4 waves, each a 64x32 quadrant (4x2 frags 16x16x32).
// global_load_lds width=16 with pre-swizzled global source (rule #21);
// XOR-swizzled ds_read_b128; 2-phase double buffer.
// ---------------------------------------------------------------------------
template<bool OUT_F32, bool RELU>
__global__ __launch_bounds__(256)
void gemm_tiled(const bf16_t* __restrict__ A, const bf16_t* __restrict__ Bt,
                const float* __restrict__ bias, void* __restrict__ C,
                int M, int Nstore, int Ks)
{
    __shared__ char lds[2][24576];          // per buf: A 16KB + B 8KB
    const int tid = threadIdx.x;
    const int w = tid >> 6, lane = tid & 63, quad = lane >> 4, l16 = lane & 15;
    const int n0 = blockIdx.x << 6;         // BN=64
    const int m0 = blockIdx.y << 7;         // BM=128
    const int wr = w >> 1, wc = w & 1;

    const int lrow  = lane >> 3;
    const int gslot = ((lane & 7) ^ lrow) << 3;
    const bf16_t* aSrc[4];
    const bf16_t* bSrc[2];
    #pragma unroll
    for (int i = 0; i < 4; i++) {
        int r = m0 + (w * 4 + i) * 8 + lrow;
        if (r > M - 1) r = M - 1;
        aSrc[i] = A + (size_t)r * Ks + gslot;
    }
    #pragma unroll
    for (int i = 0; i < 2; i++)
        bSrc[i] = Bt + (size_t)(n0 + (w * 2 + i) * 8 + lrow) * Ks + gslot;

    f32x4 acc[4][2];
    #pragma unroll
    for (int m = 0; m < 4; m++)
        #pragma unroll
        for (int n = 0; n < 2; n++) acc[m][n] = (f32x4){0.f, 0.f, 0.f, 0.f};

    const int nkt = Ks >> 6;

    #define STAGE(p, kt) do {                                                  \
        const int _k0 = (kt) << 6;                                             \
        char* _b = &lds[p][0];                                                 \
        _Pragma("unroll")                                                      \
        for (int _i = 0; _i < 4; _i++)                                         \
            __builtin_amdgcn_global_load_lds(                                  \
                (const __attribute__((address_space(1))) void*)(aSrc[_i] + _k0),\
                (__attribute__((address_space(3))) void*)(_b + (w * 4 + _i) * 1024), \
                16, 0, 0);                                                     \
        _Pragma("unroll")                                                      \
        for (int _i = 0; _i < 2; _i++)                                         \
            __builtin_amdgcn_global_load_lds(                                  \
                (const __attribute__((address_space(1))) void*)(bSrc[_i] + _k0),\
                (__attribute__((address_space(3))) void*)(_b + 16384 + (w * 2 + _i) * 1024), \
                16, 0, 0);                                                     \
    } while (0)

    STAGE(0, 0);
    __syncthreads();

    for (int kt = 0; kt < nkt; kt++) {
        const int p = kt & 1;
        if (kt + 1 < nkt) STAGE(p ^ 1, kt + 1);
        const char* ab = &lds[p][0];
        #pragma unroll
        for (int kk = 0; kk < 2; kk++) {
            const int ts = (kk << 2) + quad;
            bf16x8 a[4], b[2];
            #pragma unroll
            for (int m = 0; m < 4; m++) {
                const int r = wr * 64 + m * 16 + l16;
                a[m] = *(const bf16x8*)(ab + r * 128 + ((ts ^ (r & 7)) << 4));
            }
            #pragma unroll
            for (int n = 0; n < 2; n++) {
                const int r = wc * 32 + n * 16 + l16;
                b[n] = *(const bf16x8*)(ab + 16384 + r * 128 + ((ts ^ (r & 7)) << 4));
            }
            #pragma unroll
            for (int m = 0; m < 4; m++)
                #pragma unroll
                for (int n = 0; n < 2; n++)
                    acc[m][n] = __builtin_amdgcn_mfma_f32_16x16x32_bf16(a[m], b[n], acc[m][n], 0, 0, 0);
        }
        __syncthreads();
    }
    #undef STAGE

    #pragma unroll
    for (int n = 0; n < 2; n++) {
        const int col = n0 + wc * 32 + n * 16 + l16;
        if (col >= Nstore) continue;
        const float bv = bias ? bias[col] : 0.f;
        #pragma unroll
        for (int m = 0; m < 4; m++) {
            #pragma unroll
            for (int i = 0; i < 4; i++) {
                const int mg = m0 + wr * 64 + m * 16 + quad * 4 + i;
                if (mg < M) {
                    float v = acc[m][n][i] + bv;
                    if (RELU) v = v > 0.f ? v : 0.f;
                    if (OUT_F32) ((float*)C)[(size_t)mg * Nstore + col] = v;
                    else         ((bf16_t*)C)[(size_t)mg * Nstore + col] = (bf16_t)v;
                }
            }
        }
    }
}

// ---------------------------------------------------------------------------
// Fused SRU layer: staged GEMM (M=80 = 4 batches, N=192 = 3 gates x 64 h,
// K=1024) + in-block recurrence. GEMM uses the verified m97 staging: dbuf
// BK=64, global_load_lds w16, pre-swizzled source + XOR'd ds_read_b128.
// Wave w owns all 5 row-frags x 3 col-frags (ctt = w*3+ct). B-tile row r
// (0..191) holds Wt row (r>>6)*HD + n0 + (r&63)  [U col = r: gate r>>6].
// Epilogue -> U fp32 in LDS (aliases dbuf, dead after last barrier), then
// the 20-step recurrence per (batch, h) thread. 69632 B dynamic LDS.
// ---------------------------------------------------------------------------
__global__ __launch_bounds__(256)
void sru_layer_fused(const bf16_t* __restrict__ hin, bf16_t* __restrict__ hout,
                     const bf16_t* __restrict__ Wt, const float* __restrict__ c0,
                     const float* __restrict__ bvec, float* __restrict__ cout)
{
    extern __shared__ char lds_raw[];
    const int tid = threadIdx.x;
    const int w = tid >> 6, lane = tid & 63, quad = lane >> 4, l16 = lane & 15;
    const int n0 = blockIdx.x << 6;      // h-col block (16 blocks)
    const int m0 = blockIdx.y * 80;      // 4 batches   (10 blocks), 800 exact

    const int lrow  = lane >> 3;
    const int gslot = ((lane & 7) ^ lrow) << 3;

    // A: 10 chunks of 8 rows; wave w stages chunks w*3+i (guarded < 10).
    const bf16_t* aSrc[3];
    #pragma unroll
    for (int i = 0; i < 3; i++) {
        int r = (w * 3 + i) * 8 + lrow;
        if (r > 79) r = 79;                       // unused-chunk clamp
        aSrc[i] = hin + (size_t)(m0 + r) * HD + gslot;
    }
    // B: 24 chunks of 8 rows; wave w stages chunks w*6+i.
    const bf16_t* bSrc[6];
    #pragma unroll
    for (int i = 0; i < 6; i++) {
        const int r = (w * 6 + i) * 8 + lrow;     // 0..191
        bSrc[i] = Wt + (size_t)((r >> 6) * HD + n0 + (r & 63)) * HD + gslot;
    }

    f32x4 acc[5][3];
    #pragma unroll
    for (int m = 0; m < 5; m++)
        #pragma unroll
        for (int n = 0; n < 3; n++) acc[m][n] = (f32x4){0.f, 0.f, 0.f, 0.f};

    #define STAGE(p, kt) do {                                                  \
        const int _k0 = (kt) << 6;                                             \
        char* _b = lds_raw + (p) * LDSB;                                       \
        _Pragma("unroll")                                                      \
        for (int _i = 0; _i < 3; _i++)                                         \
            if (w * 3 + _i < 10)                                               \
                __builtin_amdgcn_global_load_lds(                              \
                    (const __attribute__((address_space(1))) void*)(aSrc[_i] + _k0), \
                    (__attribute__((address_space(3))) void*)(_b + (w * 3 + _i) * 1024), \
                    16, 0, 0);                                                 \
        _Pragma("unroll")                                                      \
        for (int _i = 0; _i < 6; _i++)                                         \
            __builtin_amdgcn_global_load_lds(                                  \
                (const __attribute__((address_space(1))) void*)(bSrc[_i] + _k0), \
                (__attribute__((address_space(3))) void*)(_b + 10240 + (w * 6 + _i) * 1024), \
                16, 0, 0);                                                     \
    } while (0)

    STAGE(0, 0);
    __syncthreads();

    for (int kt = 0; kt < 16; kt++) {
        const int p = kt & 1;
        if (kt < 15) STAGE(p ^ 1, kt + 1);
        const char* ab = lds_raw + p * LDSB;
        const char* bb = ab + 10240;
        #pragma unroll
        for (int kk = 0; kk < 2; kk++) {
            const int ts = (kk << 2) + quad;
            bf16x8 a[5], b[3];
            #pragma unroll
            for (int m = 0; m < 5; m++) {
                const int r = m * 16 + l16;
                a[m] = *(const bf16x8*)(ab + r * 128 + ((ts ^ (r & 7)) << 4));
            }
            #pragma unroll
            for (int n = 0; n < 3; n++) {
                const int r = (w * 3 + n) * 16 + l16;
                b[n] = *(const bf16x8*)(bb + r * 128 + ((ts ^ (r & 7)) << 4));
            }
            #pragma unroll
            for (int m = 0; m < 5; m++)
                #pragma unroll
                for (int n = 0; n < 3; n++)
                    acc[m][n] = __builtin_amdgcn_mfma_f32_16x16x32_bf16(a[m], b[n], acc[m][n], 0, 0, 0);
        }
        __syncthreads();
    }
    #undef STAGE

    // epilogue: acc -> U fp32 in LDS (aliases staging dbuf; safe after barrier)
    float* Ul = (float*)lds_raw;                 // [80][UPITCH]
    #pragma unroll
    for (int m = 0; m < 5; m++)
        #pragma unroll
        for (int n = 0; n < 3; n++) {
            const int col = (w * 3 + n) * 16 + l16;
            #pragma unroll
            for (int i = 0; i < 4; i++)
                Ul[(m * 16 + quad * 4 + i) * UPITCH + col] = acc[m][n][i];
        }
    __syncthreads();

    // recurrence: thread = (local batch bl, col nn); numerics = round-0 (passed)
    const int bl = tid >> 6, nn = tid & 63, bg = blockIdx.y * 4 + bl;
    float c = c0[(size_t)bg * HD + n0 + nn];
    const float bfb = bvec[n0 + nn], brb = bvec[HD + n0 + nn];
    for (int t = 0; t < NT; t++) {
        const float* u = &Ul[(bl * NT + t) * UPITCH];
        const float xt = u[nn];
        const float uf = u[64 + nn];
        const float ur = u[128 + nn];
        const float f = 1.f / (1.f + __expf(-(uf + bfb)));
        const float r = 1.f / (1.f + __expf(-(ur + brb)));
        c = f * c + (1.f - f) * xt;
        const size_t gi = (size_t)(bg * NT + t) * HD + n0 + nn;
        const float hp = (float)hin[gi];
        hout[gi] = (bf16_t)(r * tanhf(c) + (1.f - r) * hp);
    }
    cout[(size_t)bg * HD + n0 + nn] = c;
}

// ---------------------------------------------------------------------------
extern "C" void kernel_launch(void* const* d_in, const int* in_sizes, int n_in,
                              void* d_out, int out_size, void* d_ws, size_t ws_size,
                              hipStream_t stream)
{
    const float* x      = (const float*)d_in[0];
    const float* hidden = (const float*)d_in[1];
    const float* W1     = (const float*)d_in[2];
    const float* b1     = (const float*)d_in[3];
    const float* sruW   = (const float*)d_in[4];
    const float* srub   = (const float*)d_in[5];
    const float* W3     = (const float*)d_in[6];
    const float* b3     = (const float*)d_in[7];
    const float* W4     = (const float*)d_in[8];
    const float* b4     = (const float*)d_in[9];

    float* out     = (float*)d_out;
    float* hid_out = out + (size_t)M_ROWS * NOUT;          // [12,40,1024] fp32

    // h0 (bf16) lives in d_out's out0 region (dead until final GEMM overwrites).
    bf16_t* h0 = (bf16_t*)d_out;

    // fused kernel needs 69632 B dynamic LDS (> 64 KB default cap)
    hipFuncSetAttribute((const void*)sru_layer_fused,
                        hipFuncAttributeMaxDynamicSharedMemorySize, 2 * LDSB);

    char* ws = (char*)d_ws;
    const size_t SZ_WT  = (size_t)NL * 3 * HD * HD * 2;    // 75,497,472
    const size_t SZ_W1  = (size_t)HD * 256 * 2;
    const size_t SZ_W3  = (size_t)HD * HD * 2;
    const size_t SZ_W4  = (size_t)1152 * HD * 2;
    const size_t SZ_XB  = (size_t)M_ROWS * 256 * 2;
    const size_t SZ_H   = (size_t)M_ROWS * HD * 2;
    const size_t SLOT   = (size_t)3 * HD * HD * 2;
    const size_t FAST_NEED = SZ_WT + SZ_W1 + SZ_W3 + SZ_W4 + SZ_XB + 2 * SZ_H;
    const bool fast = ws_size >= FAST_NEED;

    const dim3 blk(256);
    const int GY = (M_ROWS + 127) >> 7;                    // 7 row-blocks

    if (fast) {
        bf16_t* wt  = (bf16_t*)ws;
        bf16_t* w1t = (bf16_t*)(ws + SZ_WT);
        bf16_t* w3t = (bf16_t*)(ws + SZ_WT + SZ_W1);
        bf16_t* w4t = (bf16_t*)(ws + SZ_WT + SZ_W1 + SZ_W3);
        bf16_t* xb  = (bf16_t*)(ws + SZ_WT + SZ_W1 + SZ_W3 + SZ_W4);
        bf16_t* h1  = (bf16_t*)(ws + SZ_WT + SZ_W1 + SZ_W3 + SZ_W4 + SZ_XB);
        bf16_t* g   = (bf16_t*)(ws + SZ_WT + SZ_W1 + SZ_W3 + SZ_W4 + SZ_XB + SZ_H);

        convert_pad_x<<<M_ROWS, blk, 0, stream>>>(x, xb);
        transpose_convert<<<dim3(16, 4, 1),  blk, 0, stream>>>(W1,   w1t, FEA, HD,    256, HD);
        transpose_convert<<<dim3(48, 16, NL), blk, 0, stream>>>(sruW, wt,  HD,  3*HD, HD,  3*HD);
        transpose_convert<<<dim3(16, 16, 1), blk, 0, stream>>>(W3,   w3t, HD,  HD,   HD,  HD);
        transpose_convert<<<dim3(18, 16, 1), blk, 0, stream>>>(W4,   w4t, HD,  NOUT, HD,  1152);

        gemm_tiled<false, false><<<dim3(16, GY), blk, 0, stream>>>(xb, w1t, b1, h0, M_ROWS, HD, 256);

        for (int l = 0; l < NL; l++) {
            const bf16_t* hi = (l & 1) ? h1 : h0;
            bf16_t*       ho = (l & 1) ? h0 : h1;
            sru_layer_fused<<<dim3(16, 10), blk, 2 * LDSB, stream>>>(
                hi, ho, wt + (size_t)l * 3 * HD * HD,
                hidden + (size_t)l * NB * HD, srub + (size_t)l * 2 * HD,
                hid_out + (size_t)l * NB * HD);
        }
        gemm_tiled<false, true><<<dim3(16, GY), blk, 0, stream>>>(h0, w3t, b3, g, M_ROWS, HD, HD);
        gemm_tiled<true, false><<<dim3(18, GY), blk, 0, stream>>>(g, w4t, b4, out, M_ROWS, NOUT, HD);
    } else {
        bf16_t* slot = (bf16_t*)ws;
        bf16_t* xb   = (bf16_t*)(ws + SLOT);
        bf16_t* h1   = (bf16_t*)(ws + SLOT + SZ_XB);
        bf16_t* g    = (bf16_t*)(ws + SLOT + SZ_XB + SZ_H);

        convert_pad_x<<<M_ROWS, blk, 0, stream>>>(x, xb);
        transpose_convert<<<dim3(16, 4, 1), blk, 0, stream>>>(W1, slot, FEA, HD, 256, HD);
        gemm_tiled<false, false><<<dim3(16, GY), blk, 0, stream>>>(xb, slot, b1, h0, M_ROWS, HD, 256);

        for (int l = 0; l < NL; l++) {
            transpose_convert<<<dim3(48, 16, 1), blk, 0, stream>>>(
                sruW + (size_t)l * HD * 3 * HD, slot, HD, 3*HD, HD, 3*HD);
            const bf16_t* hi = (l & 1) ? h1 : h0;
            bf16_t*       ho = (l & 1) ? h0 : h1;
            sru_layer_fused<<<dim3(16, 10), blk, 2 * LDSB, stream>>>(
                hi, ho, slot,
                hidden + (size_t)l * NB * HD, srub + (size_t)l * 2 * HD,
                hid_out + (size_t)l * NB * HD);
        }
        transpose_convert<<<dim3(16, 16, 1), blk, 0, stream>>>(W3, slot, HD, HD, HD, HD);
        gemm_tiled<false, true><<<dim3(16, GY), blk, 0, stream>>>(h0, slot, b3, g, M_ROWS, HD, HD);
        transpose_convert<<<dim3(18, 16, 1), blk, 0, stream>>>(W4, slot, HD, NOUT, HD, 1152);
        gemm_tiled<true, false><<<dim3(18, GY), blk, 0, stream>>>(g, slot, b4, out, M_ROWS, NOUT, HD);
    }
}

// Round 4
// 544.545 us; speedup vs baseline: 2.1878x; 1.0136x over previous
//
#include <hip/hip_runtime.h>
#include <hip/hip_bf16.h>
#include <math.h>

typedef __bf16 bf16_t;
typedef __bf16 bf16x8 __attribute__((ext_vector_type(8)));
typedef float f32x4 __attribute__((ext_vector_type(4)));
typedef unsigned short u16;

#define NB   40
#define NT   20
#define FEA  200
#define HD   1024
#define NOUT 1095
#define NL   12
#define M_ROWS 800      // NB*NT
#define UPITCH 196      // fp32 pitch for U in LDS (192 + 4 pad)

// ring-4 buffer sizes
#define FBUF 36864      // fused: A 12x1024 (12288, rows padded 80->96) + B 24x1024 (24576)
#define GBUF 24576      // dense: A 16x1024 (16384) + B 8x1024 (8192)

// ---------------------------------------------------------------------------
// Transpose+convert: src fp32 logical [srcK][srcN] -> dst bf16 [Np][Kp],
// dst[n][k] = (k<srcK && n<srcN) ? src[k][n] : 0.
// ---------------------------------------------------------------------------
__global__ __launch_bounds__(256)
void transpose_convert(const float* __restrict__ src, bf16_t* __restrict__ dst,
                       int srcK, int srcN, int Kp, int Np)
{
    __shared__ u16 tile[64 * 66];
    const int t = threadIdx.x;
    src += (size_t)blockIdx.z * srcK * srcN;
    dst += (size_t)blockIdx.z * Np * Kp;
    const int n0 = blockIdx.x << 6, k0 = blockIdx.y << 6;
    {
        const int nl = t & 63, kb = (t >> 6) << 4;
        const int gn = n0 + nl;
        #pragma unroll
        for (int j = 0; j < 16; j++) {
            const int gk = k0 + kb + j;
            float v = (gk < srcK && gn < srcN) ? src[(size_t)gk * srcN + gn] : 0.f;
            bf16_t b = (bf16_t)v;
            tile[nl * 66 + kb + j] = *(const u16*)&b;
        }
    }
    __syncthreads();
    {
        const int nl = t >> 2, kg = (t & 3) << 4;
        const unsigned* tp = (const unsigned*)tile;
        const int dw = nl * 33 + (kg >> 1);
        uint4 v0, v1;
        v0.x = tp[dw+0]; v0.y = tp[dw+1]; v0.z = tp[dw+2]; v0.w = tp[dw+3];
        v1.x = tp[dw+4]; v1.y = tp[dw+5]; v1.z = tp[dw+6]; v1.w = tp[dw+7];
        bf16_t* dp = dst + (size_t)(n0 + nl) * Kp + k0 + kg;
        *(uint4*)dp = v0;
        *(uint4*)(dp + 8) = v1;
    }
}

// x [800][200] fp32 -> xb [800][256] bf16, zero-padded K.
__global__ __launch_bounds__(256)
void convert_pad_x(const float* __restrict__ src, bf16_t* __restrict__ dst)
{
    const int m = blockIdx.x, k = threadIdx.x;
    dst[m * 256 + k] = (bf16_t)((k < FEA) ? src[(size_t)m * FEA + k] : 0.f);
}

// ---------------------------------------------------------------------------
// LDS-tiled dense GEMM, ring-4 counted-vmcnt pipeline (T3+T4).
// BM=128, BN=64, BK=64; 4 waves, each a 64x32 quadrant (4x2 frags 16x16x32).
// global_load_lds w16, pre-swizzled source + XOR'd ds_read_b128 (rule #21).
// Per iter: stage tile kt+2 -> buf (kt+2)&3; s_waitcnt vmcnt(12) [tile kt's
// 6 loads/wave are oldest]; s_barrier; compute. Tail peels vmcnt(6)/(0).
// Ring-4 needed: stage target's last readers passed barrier(kt-1) (safe);
// ring-3 would race. Dynamic LDS 98304 B.
// ---------------------------------------------------------------------------
template<bool OUT_F32, bool RELU>
__global__ __launch_bounds__(256)
void gemm_tiled(const bf16_t* __restrict__ A, const bf16_t* __restrict__ Bt,
                const float* __restrict__ bias, void* __restrict__ C,
                int M, int Nstore, int Ks)
{
    extern __shared__ char lds[];           // [4][GBUF]
    const int tid = threadIdx.x;
    const int w = tid >> 6, lane = tid & 63, quad = lane >> 4, l16 = lane & 15;
    const int n0 = blockIdx.x << 6;         // BN=64
    const int m0 = blockIdx.y << 7;         // BM=128
    const int wr = w >> 1, wc = w & 1;

    const int lrow  = lane >> 3;
    const int gslot = ((lane & 7) ^ lrow) << 3;
    const bf16_t* aSrc[4];
    const bf16_t* bSrc[2];
    #pragma unroll
    for (int i = 0; i < 4; i++) {
        int r = m0 + (w * 4 + i) * 8 + lrow;
        if (r > M - 1) r = M - 1;
        aSrc[i] = A + (size_t)r * Ks + gslot;
    }
    #pragma unroll
    for (int i = 0; i < 2; i++)
        bSrc[i] = Bt + (size_t)(n0 + (w * 2 + i) * 8 + lrow) * Ks + gslot;

    f32x4 acc[4][2];
    #pragma unroll
    for (int m = 0; m < 4; m++)
        #pragma unroll
        for (int n = 0; n < 2; n++) acc[m][n] = (f32x4){0.f, 0.f, 0.f, 0.f};

    const int nkt = Ks >> 6;

    #define STAGE(kt) do {                                                     \
        const int _k0 = (kt) << 6;                                             \
        char* _b = lds + ((kt) & 3) * GBUF;                                    \
        _Pragma("unroll")                                                      \
        for (int _i = 0; _i < 4; _i++)                                         \
            __builtin_amdgcn_global_load_lds(                                  \
                (const __attribute__((address_space(1))) void*)(aSrc[_i] + _k0),\
                (__attribute__((address_space(3))) void*)(_b + (w * 4 + _i) * 1024), \
                16, 0, 0);                                                     \
        _Pragma("unroll")                                                      \
        for (int _i = 0; _i < 2; _i++)                                         \
            __builtin_amdgcn_global_load_lds(                                  \
                (const __attribute__((address_space(1))) void*)(bSrc[_i] + _k0),\
                (__attribute__((address_space(3))) void*)(_b + 16384 + (w * 2 + _i) * 1024), \
                16, 0, 0);                                                     \
    } while (0)

    STAGE(0);
    if (nkt > 1) STAGE(1);

    for (int kt = 0; kt < nkt; kt++) {
        if (kt + 2 < nkt) STAGE(kt + 2);
        const int rem = nkt - 1 - kt;
        if (rem >= 2)      asm volatile("s_waitcnt vmcnt(12)" ::: "memory");
        else if (rem == 1) asm volatile("s_waitcnt vmcnt(6)"  ::: "memory");
        else               asm volatile("s_waitcnt vmcnt(0)"  ::: "memory");
        __builtin_amdgcn_s_barrier();

        const char* ab = lds + (kt & 3) * GBUF;
        #pragma unroll
        for (int kk = 0; kk < 2; kk++) {
            const int ts = (kk << 2) + quad;
            bf16x8 a[4], b[2];
            #pragma unroll
            for (int m = 0; m < 4; m++) {
                const int r = wr * 64 + m * 16 + l16;
                a[m] = *(const bf16x8*)(ab + r * 128 + ((ts ^ (r & 7)) << 4));
            }
            #pragma unroll
            for (int n = 0; n < 2; n++) {
                const int r = wc * 32 + n * 16 + l16;
                b[n] = *(const bf16x8*)(ab + 16384 + r * 128 + ((ts ^ (r & 7)) << 4));
            }
            #pragma unroll
            for (int m = 0; m < 4; m++)
                #pragma unroll
                for (int n = 0; n < 2; n++)
                    acc[m][n] = __builtin_amdgcn_mfma_f32_16x16x32_bf16(a[m], b[n], acc[m][n], 0, 0, 0);
        }
    }
    #undef STAGE

    #pragma unroll
    for (int n = 0; n < 2; n++) {
        const int col = n0 + wc * 32 + n * 16 + l16;
        if (col >= Nstore) continue;
        const float bv = bias ? bias[col] : 0.f;
        #pragma unroll
        for (int m = 0; m < 4; m++) {
            #pragma unroll
            for (int i = 0; i < 4; i++) {
                const int mg = m0 + wr * 64 + m * 16 + quad * 4 + i;
                if (mg < M) {
                    float v = acc[m][n][i] + bv;
                    if (RELU) v = v > 0.f ? v : 0.f;
                    if (OUT_F32) ((float*)C)[(size_t)mg * Nstore + col] = v;
                    else         ((bf16_t*)C)[(size_t)mg * Nstore + col] = (bf16_t)v;
                }
            }
        }
    }
}

// ---------------------------------------------------------------------------
// Fused SRU layer, ring-4 counted-vmcnt pipeline. GEMM M=80 (4 batches),
// N=192 (3 gates x 64 h), K=1024, nkt=16. A-tile padded to 96 rows (12
// chunks) so every wave stages exactly 9 loads (3 A + 6 B) -> uniform vmcnt.
// Per iter: stage kt+2; vmcnt(18); s_barrier; compute. Tail vmcnt(9)/(0).
// Epilogue: U fp32 -> LDS (aliases ring bufs 0-1, 62720 <= 73728), then
// 20-step recurrence. Dynamic LDS 147456 B.
// ---------------------------------------------------------------------------
__global__ __launch_bounds__(256)
void sru_layer_fused(const bf16_t* __restrict__ hin, bf16_t* __restrict__ hout,
                     const bf16_t* __restrict__ Wt, const float* __restrict__ c0,
                     const float* __restrict__ bvec, float* __restrict__ cout)
{
    extern __shared__ char lds_raw[];       // [4][FBUF]
    const int tid = threadIdx.x;
    const int w = tid >> 6, lane = tid & 63, quad = lane >> 4, l16 = lane & 15;
    const int n0 = blockIdx.x << 6;      // h-col block (16 blocks)
    const int m0 = blockIdx.y * 80;      // 4 batches   (10 blocks)

    const int lrow  = lane >> 3;
    const int gslot = ((lane & 7) ^ lrow) << 3;

    // A: 12 chunks of 8 rows (rows 80..95 clamped -> duplicate loads of row
    // 79, never read back); wave w stages chunks w*3+i.
    const bf16_t* aSrc[3];
    #pragma unroll
    for (int i = 0; i < 3; i++) {
        int r = (w * 3 + i) * 8 + lrow;
        if (r > 79) r = 79;
        aSrc[i] = hin + (size_t)(m0 + r) * HD + gslot;
    }
    // B: 24 chunks of 8 rows; wave w stages chunks w*6+i. B-tile row r
    // (0..191) = Wt row (r>>6)*HD + n0 + (r&63).
    const bf16_t* bSrc[6];
    #pragma unroll
    for (int i = 0; i < 6; i++) {
        const int r = (w * 6 + i) * 8 + lrow;
        bSrc[i] = Wt + (size_t)((r >> 6) * HD + n0 + (r & 63)) * HD + gslot;
    }

    f32x4 acc[5][3];
    #pragma unroll
    for (int m = 0; m < 5; m++)
        #pragma unroll
        for (int n = 0; n < 3; n++) acc[m][n] = (f32x4){0.f, 0.f, 0.f, 0.f};

    #define STAGEF(kt) do {                                                    \
        const int _k0 = (kt) << 6;                                             \
        char* _b = lds_raw + ((kt) & 3) * FBUF;                                \
        _Pragma("unroll")                                                      \
        for (int _i = 0; _i < 3; _i++)                                         \
            __builtin_amdgcn_global_load_lds(                                  \
                (const __attribute__((address_space(1))) void*)(aSrc[_i] + _k0), \
                (__attribute__((address_space(3))) void*)(_b + (w * 3 + _i) * 1024), \
                16, 0, 0);                                                     \
        _Pragma("unroll")                                                      \
        for (int _i = 0; _i < 6; _i++)                                         \
            __builtin_amdgcn_global_load_lds(                                  \
                (const __attribute__((address_space(1))) void*)(bSrc[_i] + _k0), \
                (__attribute__((address_space(3))) void*)(_b + 12288 + (w * 6 + _i) * 1024), \
                16, 0, 0);                                                     \
    } while (0)

    STAGEF(0);
    STAGEF(1);

    for (int kt = 0; kt < 16; kt++) {
        if (kt + 2 < 16) STAGEF(kt + 2);
        const int rem = 15 - kt;
        if (rem >= 2)      asm volatile("s_waitcnt vmcnt(18)" ::: "memory");
        else if (rem == 1) asm volatile("s_waitcnt vmcnt(9)"  ::: "memory");
        else               asm volatile("s_waitcnt vmcnt(0)"  ::: "memory");
        __builtin_amdgcn_s_barrier();

        const char* ab = lds_raw + (kt & 3) * FBUF;
        const char* bb = ab + 12288;
        #pragma unroll
        for (int kk = 0; kk < 2; kk++) {
            const int ts = (kk << 2) + quad;
            bf16x8 a[5], b[3];
            #pragma unroll
            for (int m = 0; m < 5; m++) {
                const int r = m * 16 + l16;
                a[m] = *(const bf16x8*)(ab + r * 128 + ((ts ^ (r & 7)) << 4));
            }
            #pragma unroll
            for (int n = 0; n < 3; n++) {
                const int r = (w * 3 + n) * 16 + l16;
                b[n] = *(const bf16x8*)(bb + r * 128 + ((ts ^ (r & 7)) << 4));
            }
            #pragma unroll
            for (int m = 0; m < 5; m++)
                #pragma unroll
                for (int n = 0; n < 3; n++)
                    acc[m][n] = __builtin_amdgcn_mfma_f32_16x16x32_bf16(a[m], b[n], acc[m][n], 0, 0, 0);
        }
    }
    #undef STAGEF

    // epilogue: acc -> U fp32 in LDS (ring bufs 0-1 region; all reads of
    // bufs 0/1 completed before barrier(14)/(15); other waves still in
    // compute 15 read buf 3 -> disjoint).
    float* Ul = (float*)lds_raw;                 // [80][UPITCH]
    #pragma unroll
    for (int m = 0; m < 5; m++)
        #pragma unroll
        for (int n = 0; n < 3; n++) {
            const int col = (w * 3 + n) * 16 + l16;
            #pragma unroll
            for (int i = 0; i < 4; i++)
                Ul[(m * 16 + quad * 4 + i) * UPITCH + col] = acc[m][n][i];
        }
    __syncthreads();

    // recurrence: thread = (local batch bl, col nn); numerics = round-0
    const int bl = tid >> 6, nn = tid & 63, bg = blockIdx.y * 4 + bl;
    float c = c0[(size_t)bg * HD + n0 + nn];
    const float bfb = bvec[n0 + nn], brb = bvec[HD + n0 + nn];
    for (int t = 0; t < NT; t++) {
        const float* u = &Ul[(bl * NT + t) * UPITCH];
        const float xt = u[nn];
        const float uf = u[64 + nn];
        const float ur = u[128 + nn];
        const float f = 1.f / (1.f + __expf(-(uf + bfb)));
        const float r = 1.f / (1.f + __expf(-(ur + brb)));
        c = f * c + (1.f - f) * xt;
        const size_t gi = (size_t)(bg * NT + t) * HD + n0 + nn;
        const float hp = (float)hin[gi];
        hout[gi] = (bf16_t)(r * tanhf(c) + (1.f - r) * hp);
    }
    cout[(size_t)bg * HD + n0 + nn] = c;
}

// ---------------------------------------------------------------------------
extern "C" void kernel_launch(void* const* d_in, const int* in_sizes, int n_in,
                              void* d_out, int out_size, void* d_ws, size_t ws_size,
                              hipStream_t stream)
{
    const float* x      = (const float*)d_in[0];
    const float* hidden = (const float*)d_in[1];
    const float* W1     = (const float*)d_in[2];
    const float* b1     = (const float*)d_in[3];
    const float* sruW   = (const float*)d_in[4];
    const float* srub   = (const float*)d_in[5];
    const float* W3     = (const float*)d_in[6];
    const float* b3     = (const float*)d_in[7];
    const float* W4     = (const float*)d_in[8];
    const float* b4     = (const float*)d_in[9];

    float* out     = (float*)d_out;
    float* hid_out = out + (size_t)M_ROWS * NOUT;          // [12,40,1024] fp32

    // h0 (bf16) lives in d_out's out0 region (dead until final GEMM overwrites).
    bf16_t* h0 = (bf16_t*)d_out;

    // raise dynamic-LDS caps (host-side; graph-capture safe, proven round 3)
    hipFuncSetAttribute((const void*)sru_layer_fused,
                        hipFuncAttributeMaxDynamicSharedMemorySize, 4 * FBUF);
    hipFuncSetAttribute((const void*)gemm_tiled<false, false>,
                        hipFuncAttributeMaxDynamicSharedMemorySize, 4 * GBUF);
    hipFuncSetAttribute((const void*)gemm_tiled<false, true>,
                        hipFuncAttributeMaxDynamicSharedMemorySize, 4 * GBUF);
    hipFuncSetAttribute((const void*)gemm_tiled<true, false>,
                        hipFuncAttributeMaxDynamicSharedMemorySize, 4 * GBUF);

    char* ws = (char*)d_ws;
    const size_t SZ_WT  = (size_t)NL * 3 * HD * HD * 2;    // 75,497,472
    const size_t SZ_W1  = (size_t)HD * 256 * 2;
    const size_t SZ_W3  = (size_t)HD * HD * 2;
    const size_t SZ_W4  = (size_t)1152 * HD * 2;
    const size_t SZ_XB  = (size_t)M_ROWS * 256 * 2;
    const size_t SZ_H   = (size_t)M_ROWS * HD * 2;
    const size_t SLOT   = (size_t)3 * HD * HD * 2;
    const size_t FAST_NEED = SZ_WT + SZ_W1 + SZ_W3 + SZ_W4 + SZ_XB + 2 * SZ_H;
    const bool fast = ws_size >= FAST_NEED;

    const dim3 blk(256);
    const int GY = (M_ROWS + 127) >> 7;                    // 7 row-blocks

    if (fast) {
        bf16_t* wt  = (bf16_t*)ws;
        bf16_t* w1t = (bf16_t*)(ws + SZ_WT);
        bf16_t* w3t = (bf16_t*)(ws + SZ_WT + SZ_W1);
        bf16_t* w4t = (bf16_t*)(ws + SZ_WT + SZ_W1 + SZ_W3);
        bf16_t* xb  = (bf16_t*)(ws + SZ_WT + SZ_W1 + SZ_W3 + SZ_W4);
        bf16_t* h1  = (bf16_t*)(ws + SZ_WT + SZ_W1 + SZ_W3 + SZ_W4 + SZ_XB);
        bf16_t* g   = (bf16_t*)(ws + SZ_WT + SZ_W1 + SZ_W3 + SZ_W4 + SZ_XB + SZ_H);

        convert_pad_x<<<M_ROWS, blk, 0, stream>>>(x, xb);
        transpose_convert<<<dim3(16, 4, 1),  blk, 0, stream>>>(W1,   w1t, FEA, HD,    256, HD);
        transpose_convert<<<dim3(48, 16, NL), blk, 0, stream>>>(sruW, wt,  HD,  3*HD, HD,  3*HD);
        transpose_convert<<<dim3(16, 16, 1), blk, 0, stream>>>(W3,   w3t, HD,  HD,   HD,  HD);
        transpose_convert<<<dim3(18, 16, 1), blk, 0, stream>>>(W4,   w4t, HD,  NOUT, HD,  1152);

        gemm_tiled<false, false><<<dim3(16, GY), blk, 4 * GBUF, stream>>>(xb, w1t, b1, h0, M_ROWS, HD, 256);

        for (int l = 0; l < NL; l++) {
            const bf16_t* hi = (l & 1) ? h1 : h0;
            bf16_t*       ho = (l & 1) ? h0 : h1;
            sru_layer_fused<<<dim3(16, 10), blk, 4 * FBUF, stream>>>(
                hi, ho, wt + (size_t)l * 3 * HD * HD,
                hidden + (size_t)l * NB * HD, srub + (size_t)l * 2 * HD,
                hid_out + (size_t)l * NB * HD);
        }
        gemm_tiled<false, true><<<dim3(16, GY), blk, 4 * GBUF, stream>>>(h0, w3t, b3, g, M_ROWS, HD, HD);
        gemm_tiled<true, false><<<dim3(18, GY), blk, 4 * GBUF, stream>>>(g, w4t, b4, out, M_ROWS, NOUT, HD);
    } else {
        bf16_t* slot = (bf16_t*)ws;
        bf16_t* xb   = (bf16_t*)(ws + SLOT);
        bf16_t* h1   = (bf16_t*)(ws + SLOT + SZ_XB);
        bf16_t* g    = (bf16_t*)(ws + SLOT + SZ_XB + SZ_H);

        convert_pad_x<<<M_ROWS, blk, 0, stream>>>(x, xb);
        transpose_convert<<<dim3(16, 4, 1), blk, 0, stream>>>(W1, slot, FEA, HD, 256, HD);
        gemm_tiled<false, false><<<dim3(16, GY), blk, 4 * GBUF, stream>>>(xb, slot, b1, h0, M_ROWS, HD, 256);

        for (int l = 0; l < NL; l++) {
            transpose_convert<<<dim3(48, 16, 1), blk, 0, stream>>>(
                sruW + (size_t)l * HD * 3 * HD, slot, HD, 3*HD, HD, 3*HD);
            const bf16_t* hi = (l & 1) ? h1 : h0;
            bf16_t*       ho = (l & 1) ? h0 : h1;
            sru_layer_fused<<<dim3(16, 10), blk, 4 * FBUF, stream>>>(
                hi, ho, slot,
                hidden + (size_t)l * NB * HD, srub + (size_t)l * 2 * HD,
                hid_out + (size_t)l * NB * HD);
        }
        transpose_convert<<<dim3(16, 16, 1), blk, 0, stream>>>(W3, slot, HD, HD, HD, HD);
        gemm_tiled<false, true><<<dim3(16, GY), blk, 4 * GBUF, stream>>>(h0, slot, b3, g, M_ROWS, HD, HD);
        transpose_convert<<<dim3(18, 16, 1), blk, 0, stream>>>(W4, slot, HD, NOUT, HD, 1152);
        gemm_tiled<true, false><<<dim3(18, GY), blk, 4 * GBUF, stream>>>(g, slot, b4, out, M_ROWS, NOUT, HD);
    }
}